// Round 9
// baseline (67.656 us; speedup 1.0000x reference)
//
#include <hip/hip_runtime.h>
#include <hip/hip_cooperative_groups.h>
#include <math.h>

namespace cg = cooperative_groups;

constexpr int B  = 32;
constexpr int C  = 512;
constexpr int CR = 32;            // C / R
constexpr int HW = 56 * 56;       // 3136
constexpr int NV4 = HW / 4;       // 784 float4 per row
constexpr float EPS = 1e-5f;

typedef float f32x4 __attribute__((ext_vector_type(4)));

__device__ inline f32x4 ntload(const f32x4* p) {
    return __builtin_nontemporal_load(p);
}

// Kernel 1: one wave per (b,c) row. 12 unrolled nontemporal float4 loads/lane +
// full-wave scalar tail (3136 = 12*4*64 + 64), shuffle-only reduction.
__global__ __launch_bounds__(256) void rowstats(const float* __restrict__ x,
                                                float* __restrict__ s_out,
                                                float* __restrict__ q_out) {
    const int wid  = threadIdx.x >> 6;
    const int lane = threadIdx.x & 63;
    const int row  = blockIdx.x * 4 + wid;          // grid = 4096 -> 16384 rows
    const f32x4* xp = reinterpret_cast<const f32x4*>(x) + (size_t)row * NV4 + lane;
    float s = 0.f, q = 0.f;
    #pragma unroll
    for (int i = 0; i < 12; ++i) {                   // 12*64 = 768 float4 = 3072 floats
        f32x4 v = ntload(xp + i * 64);
        s += (v.x + v.y) + (v.z + v.w);
        q += (v.x * v.x + v.y * v.y) + (v.z * v.z + v.w * v.w);
    }
    {                                                // tail: 64 floats, 1/lane
        const float v = __builtin_nontemporal_load(x + (size_t)row * HW + 3072 + lane);
        s += v;
        q = fmaf(v, v, q);
    }
    #pragma unroll
    for (int off = 32; off > 0; off >>= 1) {
        s += __shfl_down(s, off, 64);
        q += __shfl_down(q, off, 64);
    }
    if (lane == 0) {
        s_out[row] = s * (1.0f / (float)HW);
        q_out[row] = q;
    }
}

// Kernel 2 (cooperative, 32 blocks x 512 threads):
//   phase 1 = SE excitation per batch b (identical to proven excite kernel)
//   grid.sync()
//   phase 2 = BN stats + combine, spread over all 32 blocks (16 channels each).
__global__ __launch_bounds__(512) void excite_bn(const float* __restrict__ s_in,
                                                 const float* __restrict__ q_in,
                                                 const float* __restrict__ w1,
                                                 const float* __restrict__ w2,
                                                 const float* __restrict__ bnw,
                                                 const float* __restrict__ bnb,
                                                 float* __restrict__ m_ws,
                                                 float* __restrict__ eq_ws,
                                                 float* __restrict__ out) {
    const int b   = blockIdx.x;                      // gridDim.x == B == 32
    const int tid = threadIdx.x;
    __shared__ __align__(16) float sh_s[C];
    __shared__ float sh_h[CR];
    __shared__ float sh_mean[16], sh_g[16], sh_bv[16];

    // ---------- phase 1: excitation for batch b ----------
    const int j = tid >> 4, t = tid & 15;
    float4 w1r[8];
    {
        const float4* wr = reinterpret_cast<const float4*>(w1 + j * C);
        #pragma unroll
        for (int k = 0; k < 8; ++k) w1r[k] = wr[t + 16 * k];
    }
    float4 w2r[8];
    {
        const float4* w2p = reinterpret_cast<const float4*>(w2 + tid * CR);
        #pragma unroll
        for (int k = 0; k < 8; ++k) w2r[k] = w2p[k];
    }
    const float qv = q_in[b * C + tid];
    const float sv = s_in[b * C + tid];
    sh_s[tid] = sv;
    __syncthreads();

    {   // h[j] = relu(dot(s, w1[j])): 16 threads per j
        const float4* sr = reinterpret_cast<const float4*>(sh_s);
        float acc = 0.f;
        #pragma unroll
        for (int k = 0; k < 8; ++k) {
            float4 wv = w1r[k];
            float4 svv = sr[t + 16 * k];
            acc = fmaf(svv.x, wv.x, fmaf(svv.y, wv.y, fmaf(svv.z, wv.z, fmaf(svv.w, wv.w, acc))));
        }
        #pragma unroll
        for (int off = 8; off > 0; off >>= 1)
            acc += __shfl_down(acc, off, 16);
        if (t == 0) sh_h[j] = fmaxf(acc, 0.f);
    }
    __syncthreads();

    {   // e[c] = sigmoid(dot(h, w2[c])); emit m = e*s, eq = e^2*sumsq
        const float4* hp = reinterpret_cast<const float4*>(sh_h);
        float acc = 0.f;
        #pragma unroll
        for (int k = 0; k < CR / 4; ++k) {
            float4 wv = w2r[k];
            float4 hv = hp[k];
            acc = fmaf(hv.x, wv.x, fmaf(hv.y, wv.y, fmaf(hv.z, wv.z, fmaf(hv.w, wv.w, acc))));
        }
        const float e = 1.0f / (1.0f + expf(-acc));
        m_ws[b * C + tid]  = e * sv;
        eq_ws[b * C + tid] = e * e * qv;
    }

    // ---------- grid-wide sync ----------
    __threadfence();
    cg::this_grid().sync();

    // ---------- phase 2: BN stats + combine; block handles 8 c2-pairs ----------
    const int base = blockIdx.x * 8;                 // c2 in [base, base+8)
    {
        // Stats for 16 channels: k<8 -> ca=base+k, k>=8 -> cb=256+base+k-8.
        const int k  = tid >> 5;                     // 0..15
        const int bb = tid & 31;
        const int chan = (k < 8) ? (base + k) : (C / 2 + base + (k - 8));
        float mvv = m_ws[bb * C + chan];
        float evv = eq_ws[bb * C + chan];
        #pragma unroll
        for (int off = 16; off > 0; off >>= 1) {
            mvv += __shfl_down(mvv, off, 32);
            evv += __shfl_down(evv, off, 32);
        }
        if (bb == 0) {
            const float mean = mvv * (1.0f / (float)B);
            const float var  = evv * (1.0f / ((float)B * (float)HW)) - mean * mean;
            sh_mean[k] = mean;
            sh_g[k]    = bnw[chan] * rsqrtf(var + EPS);
            sh_bv[k]   = bnb[chan];
        }
    }
    __syncthreads();

    // 8 c2 x 32 b = 256 outputs; threads 0..255, one output each.
    if (tid < 256) {
        const int bb = tid & 31;
        const int i  = tid >> 5;                     // 0..7
        const int ca = base + i;
        const int cb = C / 2 + base + i;
        const float ma = m_ws[bb * C + ca];          // L2-hot
        const float mb = m_ws[bb * C + cb];
        out[bb * (C / 2) + ca] =
            (ma - sh_mean[i])     * sh_g[i]     + sh_bv[i] +
            (mb - sh_mean[i + 8]) * sh_g[i + 8] + sh_bv[i + 8];
    }
}

extern "C" void kernel_launch(void* const* d_in, const int* in_sizes, int n_in,
                              void* d_out, int out_size, void* d_ws, size_t ws_size,
                              hipStream_t stream) {
    const float* x   = (const float*)d_in[0];
    const float* w1  = (const float*)d_in[1];
    const float* w2  = (const float*)d_in[2];
    const float* bnw = (const float*)d_in[3];
    const float* bnb = (const float*)d_in[4];
    float* out = (float*)d_out;

    float* s_ws  = (float*)d_ws;          // B*C floats (row means)
    float* q_ws  = s_ws + B * C;          // B*C floats (row sum of squares)
    float* m_ws  = q_ws + B * C;          // B*C floats (e*s)
    float* eq_ws = m_ws + B * C;          // B*C floats (e^2 * sumsq)

    rowstats<<<dim3(B * C / 4), dim3(256), 0, stream>>>(x, s_ws, q_ws);

    void* args[] = {(void*)&s_ws, (void*)&q_ws, (void*)&w1, (void*)&w2,
                    (void*)&bnw, (void*)&bnb, (void*)&m_ws, (void*)&eq_ws,
                    (void*)&out};
    hipLaunchCooperativeKernel((const void*)excite_bn, dim3(B), dim3(512),
                               args, 0, stream);
}

// Round 10
// 40.218 us; speedup vs baseline: 1.6822x; 1.6822x over previous
//
#include <hip/hip_runtime.h>
#include <math.h>

constexpr int B  = 32;
constexpr int C  = 512;
constexpr int CR = 32;            // C / R
constexpr int HW = 56 * 56;       // 3136
constexpr int NV4 = HW / 4;       // 784 float4 per row
constexpr float EPS = 1e-5f;

typedef float f32x4 __attribute__((ext_vector_type(4)));

__device__ inline f32x4 ntload(const f32x4* p) {
    return __builtin_nontemporal_load(p);
}

// Kernel 1: one wave per (b,c) row. 12 unrolled nontemporal float4 loads/lane +
// full-wave scalar tail (3136 = 12*4*64 + 64), shuffle-only reduction.
__global__ __launch_bounds__(256) void rowstats(const float* __restrict__ x,
                                                float* __restrict__ s_out,
                                                float* __restrict__ q_out) {
    const int wid  = threadIdx.x >> 6;
    const int lane = threadIdx.x & 63;
    const int row  = blockIdx.x * 4 + wid;          // grid = 4096 -> 16384 rows
    const f32x4* xp = reinterpret_cast<const f32x4*>(x) + (size_t)row * NV4 + lane;
    float s = 0.f, q = 0.f;
    #pragma unroll
    for (int i = 0; i < 12; ++i) {                   // 12*64 = 768 float4 = 3072 floats
        f32x4 v = ntload(xp + i * 64);
        s += (v.x + v.y) + (v.z + v.w);
        q += (v.x * v.x + v.y * v.y) + (v.z * v.z + v.w * v.w);
    }
    {                                                // tail: 64 floats, 1/lane, no divergence
        const float v = __builtin_nontemporal_load(x + (size_t)row * HW + 3072 + lane);
        s += v;
        q = fmaf(v, v, q);
    }
    #pragma unroll
    for (int off = 32; off > 0; off >>= 1) {
        s += __shfl_down(s, off, 64);
        q += __shfl_down(q, off, 64);
    }
    if (lane == 0) {
        s_out[row] = s * (1.0f / (float)HW);
        q_out[row] = q;
    }
}

// Kernel 2: SE excitation, one block per batch element b (32 blocks, 512 threads).
// Weight/q loads are issued BEFORE the s-staging barrier to hide HBM latency.
__global__ __launch_bounds__(512) void excite(const float* __restrict__ s_in,
                                              const float* __restrict__ q_in,
                                              const float* __restrict__ w1,
                                              const float* __restrict__ w2,
                                              float* __restrict__ m_out,
                                              float* __restrict__ eq_out) {
    const int b   = blockIdx.x;
    const int tid = threadIdx.x;
    __shared__ __align__(16) float sh_s[C];
    __shared__ float sh_h[CR];

    const int j = tid >> 4, t = tid & 15;

    // --- Issue all global loads up front (independent of s), then stage s.
    float4 w1r[8];
    {
        const float4* wr = reinterpret_cast<const float4*>(w1 + j * C);
        #pragma unroll
        for (int k = 0; k < 8; ++k) w1r[k] = wr[t + 16 * k];
    }
    float4 w2r[8];
    {
        const float4* w2p = reinterpret_cast<const float4*>(w2 + tid * CR);
        #pragma unroll
        for (int k = 0; k < 8; ++k) w2r[k] = w2p[k];
    }
    const float qv = q_in[b * C + tid];
    const float sv = s_in[b * C + tid];
    sh_s[tid] = sv;                                  // coalesced
    __syncthreads();

    // h[j] = relu(dot(s, w1[j])): 16 threads per j (tid = j*16 + t).
    {
        const float4* sr = reinterpret_cast<const float4*>(sh_s);
        float acc = 0.f;
        #pragma unroll
        for (int k = 0; k < 8; ++k) {                // 8 * 16 = 128 float4 = 512 floats
            float4 wv = w1r[k];
            float4 svv = sr[t + 16 * k];
            acc = fmaf(svv.x, wv.x, fmaf(svv.y, wv.y, fmaf(svv.z, wv.z, fmaf(svv.w, wv.w, acc))));
        }
        #pragma unroll
        for (int off = 8; off > 0; off >>= 1)
            acc += __shfl_down(acc, off, 16);
        if (t == 0) sh_h[j] = fmaxf(acc, 0.f);
    }
    __syncthreads();

    // e[c] = sigmoid(dot(h, w2[c])) per thread c; emit m = e*s and eq = e^2*sumsq.
    {
        const float4* hp = reinterpret_cast<const float4*>(sh_h);
        float acc = 0.f;
        #pragma unroll
        for (int k = 0; k < CR / 4; ++k) {
            float4 wv = w2r[k];
            float4 hv = hp[k];                       // LDS broadcast
            acc = fmaf(hv.x, wv.x, fmaf(hv.y, wv.y, fmaf(hv.z, wv.z, fmaf(hv.w, wv.w, acc))));
        }
        const float e = 1.0f / (1.0f + expf(-acc));
        m_out[b * C + tid]  = e * sv;
        eq_out[b * C + tid] = e * e * qv;
    }
}

// Kernel 3: BN stats + final combine. One block, 512 threads (thread = channel c).
__global__ __launch_bounds__(512) void bnout(const float* __restrict__ m_in,
                                             const float* __restrict__ eq_in,
                                             const float* __restrict__ bnw,
                                             const float* __restrict__ bnb,
                                             float* __restrict__ out) {
    const int c = threadIdx.x;
    __shared__ float sh_z[B][C / 2];                 // first-half normalized vals
    const float wv = bnw[c];
    const float bv = bnb[c];
    float mv[B];
    float mean = 0.f, eq = 0.f;
    #pragma unroll
    for (int b = 0; b < B; ++b) {                    // coalesced, L2-hit
        mv[b] = m_in[b * C + c];
        eq   += eq_in[b * C + c];
        mean += mv[b];
    }
    mean *= (1.0f / (float)B);
    const float var = eq * (1.0f / ((float)B * (float)HW)) - mean * mean;
    const float g   = wv * rsqrtf(var + EPS);

    if (c < C / 2) {
        #pragma unroll
        for (int b = 0; b < B; ++b)
            sh_z[b][c] = (mv[b] - mean) * g + bv;
    }
    __syncthreads();
    if (c >= C / 2) {
        const int c2 = c - C / 2;
        #pragma unroll
        for (int b = 0; b < B; ++b)
            out[b * (C / 2) + c2] = sh_z[b][c2] + ((mv[b] - mean) * g + bv);
    }
}

extern "C" void kernel_launch(void* const* d_in, const int* in_sizes, int n_in,
                              void* d_out, int out_size, void* d_ws, size_t ws_size,
                              hipStream_t stream) {
    const float* x   = (const float*)d_in[0];
    const float* w1  = (const float*)d_in[1];
    const float* w2  = (const float*)d_in[2];
    const float* bnw = (const float*)d_in[3];
    const float* bnb = (const float*)d_in[4];
    float* out = (float*)d_out;

    float* s_ws  = (float*)d_ws;          // B*C floats (row means)
    float* q_ws  = s_ws + B * C;          // B*C floats (row sum of squares)
    float* m_ws  = q_ws + B * C;          // B*C floats (e*s)
    float* eq_ws = m_ws + B * C;          // B*C floats (e^2 * sumsq)

    rowstats<<<dim3(B * C / 4), dim3(256), 0, stream>>>(x, s_ws, q_ws);
    excite<<<dim3(B), dim3(512), 0, stream>>>(s_ws, q_ws, w1, w2, m_ws, eq_ws);
    bnout<<<dim3(1), dim3(512), 0, stream>>>(m_ws, eq_ws, bnw, bnb, out);
}